// Round 5
// baseline (103.712 us; speedup 1.0000x reference)
//
#include <hip/hip_runtime.h>
#include <math.h>

#define BATCH 64
#define NNODE 1024
#define FDIM 64
#define DEG 8
#define ALPHA 0.2f
#define HSTR 66   // bf16 row stride for h in LDS (pad: gather reads 2-way=free)
#define WSTR 65   // f32 row stride for W in LDS (pad: frag reads 2-way=free)

typedef __attribute__((ext_vector_type(8))) short bf16x8;  // 8 bf16 in 4 VGPRs
typedef __attribute__((ext_vector_type(4))) float f32x4;

__device__ __forceinline__ short f2bf(float f) {
    union { float f; unsigned u; } v; v.f = f;
    unsigned r = v.u + 0x7fffu + ((v.u >> 16) & 1u);   // RNE
    return (short)(r >> 16);
}
__device__ __forceinline__ float bf2f(unsigned short s) {
    union { unsigned u; float f; } v; v.u = ((unsigned)s) << 16;
    return v.f;
}

// One block = one (batch, chunk-of-256-rows). Computes the FULL batch's
// h = bf16(atoms @ W) into LDS via MFMA (plus s1/s2 via an extra B-tile),
// then masked-softmax + gather entirely from LDS for its 256 rows.
__global__ __launch_bounds__(1024) void gat_fused(
    const float* __restrict__ atoms,   // (B*N, 64)
    const int*   __restrict__ edges,   // (B*N, 8) int32
    const float* __restrict__ W,       // (64, 64)
    const float* __restrict__ a,       // (128,)
    float* __restrict__ out)           // (B*N, 64)
{
    extern __shared__ char smem[];
    unsigned short* hl  = (unsigned short*)smem;                  // 1024*66*2 = 132 KB
    float*          Wl  = (float*)(smem + NNODE * HSTR * 2);      // 64*65*4 = 16.25 KB
    float*          s1l = Wl + FDIM * WSTR;                       // 4 KB
    float*          s2l = s1l + NNODE;                            // 4 KB
    float*          waL = s2l + NNODE;                            // 512 B

    const int tid = threadIdx.x;
    const int bid = blockIdx.x;
    // XCD swizzle: the 4 chunks of batch b share blockIdx%8 -> same XCD L2.
    const int xcd = bid & 7, kk = bid >> 3;          // kk 0..31
    const int b     = xcd * 8 + (kk & 7);            // 0..63
    const int chunk = kk >> 3;                       // 0..3

    // ---- stage W (padded) into LDS, coalesced ----
    #pragma unroll
    for (int i = 0; i < 4; ++i) {
        const int idx = tid + 1024 * i;              // 0..4095
        Wl[(idx >> 6) * WSTR + (idx & 63)] = W[idx];
    }
    __syncthreads();

    const int lane = tid & 63;
    const int wvu  = __builtin_amdgcn_readfirstlane(tid >> 6);   // 0..15, uniform
    const int l16  = lane & 15;
    const int qd   = lane >> 4;

    // ---- wave 0/1 threads compute wa1/wa2 = W @ a1/2 into LDS ----
    if (tid < 2 * FDIM) {
        const int which = tid >> 6, kr = tid & 63;
        float p = 0.f;
        #pragma unroll
        for (int j = 0; j < FDIM; ++j)
            p = fmaf(Wl[kr * WSTR + j], a[which * FDIM + j], p);
        waL[which * FDIM + kr] = p;
    }

    // ---- build W B-frags from LDS (overlaps with wa compute) ----
    bf16x8 Bw[2][4];
    #pragma unroll
    for (int ks = 0; ks < 2; ++ks)
        #pragma unroll
        for (int t = 0; t < 4; ++t)
            #pragma unroll
            for (int j = 0; j < 8; ++j)
                Bw[ks][t][j] = f2bf(Wl[(ks * 32 + qd * 8 + j) * WSTR + t * 16 + l16]);

    __syncthreads();   // waL ready

    // score B-frag: col0 = wa1[k], col1 = wa2[k], cols 2..15 = 0
    bf16x8 Bs[2];
    #pragma unroll
    for (int ks = 0; ks < 2; ++ks)
        #pragma unroll
        for (int j = 0; j < 8; ++j) {
            const int k = ks * 32 + qd * 8 + j;
            const float v = (l16 == 0) ? waL[k] : ((l16 == 1) ? waL[FDIM + k] : 0.f);
            Bs[ks][j] = f2bf(v);
        }

    // ---- GEMM: this wave computes rows [wvu*64, wvu*64+64) of the batch ----
    const float* __restrict__ ab = atoms + (size_t)b * NNODE * FDIM;
    #pragma unroll
    for (int t4 = 0; t4 < 4; ++t4) {
        const int rowbase = wvu * 64 + t4 * 16;      // node index base
        const float* __restrict__ ar = ab + (size_t)(rowbase + l16) * FDIM;

        bf16x8 A[2];
        #pragma unroll
        for (int ks = 0; ks < 2; ++ks) {
            const float4 p0 = *(const float4*)(ar + ks * 32 + qd * 8);
            const float4 p1 = *(const float4*)(ar + ks * 32 + qd * 8 + 4);
            A[ks][0] = f2bf(p0.x); A[ks][1] = f2bf(p0.y);
            A[ks][2] = f2bf(p0.z); A[ks][3] = f2bf(p0.w);
            A[ks][4] = f2bf(p1.x); A[ks][5] = f2bf(p1.y);
            A[ks][6] = f2bf(p1.z); A[ks][7] = f2bf(p1.w);
        }

        f32x4 C[4] = {{0,0,0,0},{0,0,0,0},{0,0,0,0},{0,0,0,0}};
        f32x4 Cs = {0,0,0,0};
        #pragma unroll
        for (int ks = 0; ks < 2; ++ks) {
            #pragma unroll
            for (int t = 0; t < 4; ++t)
                C[t] = __builtin_amdgcn_mfma_f32_16x16x32_bf16(A[ks], Bw[ks][t], C[t], 0, 0, 0);
            Cs = __builtin_amdgcn_mfma_f32_16x16x32_bf16(A[ks], Bs[ks], Cs, 0, 0, 0);
        }

        // C/D layout: col = l16, row = qd*4 + r
        #pragma unroll
        for (int t = 0; t < 4; ++t)
            #pragma unroll
            for (int r = 0; r < 4; ++r)
                hl[(rowbase + qd * 4 + r) * HSTR + t * 16 + l16] =
                    (unsigned short)f2bf(C[t][r]);

        if (l16 == 0) {
            #pragma unroll
            for (int r = 0; r < 4; ++r) s1l[rowbase + qd * 4 + r] = Cs[r];
        } else if (l16 == 1) {
            #pragma unroll
            for (int r = 0; r < 4; ++r) s2l[rowbase + qd * 4 + r] = Cs[r];
        }
    }
    __syncthreads();   // hl, s1l, s2l ready

    // ---- phase 2: softmax over <=8 unique neighbors, gather from LDS ----
    const int nodebase = chunk * 256 + wvu * 16;     // this wave's 16 rows
    #pragma unroll 2
    for (int i = 0; i < 16; ++i) {
        const int node = nodebase + i;               // node index in batch
        const int grow = b * NNODE + node;           // global row

        int ej[DEG];
        const int* __restrict__ ep = edges + (size_t)grow * DEG;
        #pragma unroll
        for (int k = 0; k < DEG; ++k) ej[k] = ep[k];  // uniform -> scalar loads

        const float si = s1l[node];
        float e[DEG], mx = -INFINITY;
        #pragma unroll
        for (int k = 0; k < DEG; ++k) {
            float v = si + s2l[ej[k]];
            v = (v > 0.f) ? v : ALPHA * v;           // LeakyReLU
            e[k] = v; mx = fmaxf(mx, v);
        }
        float wgt[DEG], wsum = 0.f;
        #pragma unroll
        for (int k = 0; k < DEG; ++k) {
            bool kp = true;                           // dedupe: adj is boolean
            #pragma unroll
            for (int m = 0; m < DEG; ++m)
                if (m < k && ej[m] == ej[k]) kp = false;
            const float w = kp ? __expf(e[k] - mx) : 0.f;
            wgt[k] = w; wsum += w;
        }
        const float inv = 1.f / wsum;

        float acc = 0.f;
        #pragma unroll
        for (int k = 0; k < DEG; ++k)
            acc = fmaf(wgt[k] * inv, bf2f(hl[ej[k] * HSTR + lane]), acc);

        out[(size_t)grow * FDIM + lane] = (acc > 0.f) ? acc : (__expf(acc) - 1.f);
    }
}

extern "C" void kernel_launch(void* const* d_in, const int* in_sizes, int n_in,
                              void* d_out, int out_size, void* d_ws, size_t ws_size,
                              hipStream_t stream) {
    const float* atoms = (const float*)d_in[0];   // (64,1024,64) f32
    const int*   edges = (const int*)d_in[1];     // (64,1024,8) int32
    const float* W     = (const float*)d_in[2];   // (64,64) f32
    const float* a     = (const float*)d_in[3];   // (128,1) f32
    float* out = (float*)d_out;                   // (64,1024,64) f32

    const size_t lds_bytes =
        (size_t)NNODE * HSTR * 2 +                 // hl  (bf16)
        ((size_t)FDIM * WSTR + 2 * NNODE + 2 * FDIM) * 4;  // Wl + s1l + s2l + waL
    // = 160512 B <= 160 KiB

    gat_fused<<<BATCH * 4, 1024, lds_bytes, stream>>>(atoms, edges, W, a, out);
}

// Round 6
// 103.694 us; speedup vs baseline: 1.0002x; 1.0002x over previous
//
#include <hip/hip_runtime.h>
#include <math.h>

#define BATCH 64
#define NNODE 1024
#define FDIM 64
#define DEG 8
#define ALPHA 0.2f
#define WSTR 65   // f32 row stride for W in LDS (pad)

typedef __attribute__((ext_vector_type(8))) short bf16x8;  // 8 bf16 in 4 VGPRs
typedef __attribute__((ext_vector_type(4))) float f32x4;

__device__ __forceinline__ short f2bf(float f) {
    union { float f; unsigned u; } v; v.f = f;
    unsigned r = v.u + 0x7fffu + ((v.u >> 16) & 1u);   // RNE
    return (short)(r >> 16);
}
__device__ __forceinline__ float bf2f(unsigned short s) {
    union { unsigned u; float f; } v; v.u = ((unsigned)s) << 16;
    return v.f;
}

// ---- k1: h(bf16) = atoms @ W via MFMA; s1,s2 via extra score B-tile -------
// 256 threads = 4 waves; each wave 16 rows -> 64 rows/block; grid 1024.
// Block bid handles batch b = bid&63 (so bid == b mod 8 -> XCD-local h).
__global__ __launch_bounds__(256) void gat_k1(
    const float* __restrict__ atoms,   // (B*N, 64)
    const float* __restrict__ W,       // (64, 64)
    const float* __restrict__ a,       // (128,)
    unsigned short* __restrict__ hg,   // (B*N, 64) bf16
    float* __restrict__ s1,            // (B*N)
    float* __restrict__ s2)            // (B*N)
{
    __shared__ float Wl[FDIM * WSTR];  // 16.25 KB
    __shared__ float waL[2 * FDIM];

    const int tid = threadIdx.x;
    const int bid = blockIdx.x;
    const int b     = bid & 63;
    const int chunk = bid >> 6;                       // 0..15

    // stage W (padded), coalesced
    #pragma unroll
    for (int i = 0; i < 16; ++i) {
        const int idx = tid + 256 * i;                // 0..4095
        Wl[(idx >> 6) * WSTR + (idx & 63)] = W[idx];
    }
    __syncthreads();

    const int lane = tid & 63;
    const int wv   = __builtin_amdgcn_readfirstlane(tid >> 6);
    const int l16  = lane & 15;
    const int qd   = lane >> 4;

    // threads 0..127: wa[which][kr] = sum_j W[kr][j] * a[which*64 + j]
    if (tid < 2 * FDIM) {
        const int which = tid >> 6, kr = tid & 63;
        float p = 0.f;
        #pragma unroll
        for (int j = 0; j < FDIM; ++j)
            p = fmaf(Wl[kr * WSTR + j], a[which * FDIM + j], p);
        waL[which * FDIM + kr] = p;
    }

    // W B-frags from LDS (needs only Wl; overlaps wa compute)
    bf16x8 Bw[2][4];
    #pragma unroll
    for (int ks = 0; ks < 2; ++ks)
        #pragma unroll
        for (int t = 0; t < 4; ++t)
            #pragma unroll
            for (int j = 0; j < 8; ++j)
                Bw[ks][t][j] = f2bf(Wl[(ks * 32 + qd * 8 + j) * WSTR + t * 16 + l16]);

    __syncthreads();   // waL ready

    // score B-frag: col0 = wa1[k], col1 = wa2[k]
    bf16x8 Bs[2];
    #pragma unroll
    for (int ks = 0; ks < 2; ++ks)
        #pragma unroll
        for (int j = 0; j < 8; ++j) {
            const int k = ks * 32 + qd * 8 + j;
            const float v = (l16 == 0) ? waL[k] : ((l16 == 1) ? waL[FDIM + k] : 0.f);
            Bs[ks][j] = f2bf(v);
        }

    // this wave's 16 rows
    const int grow0 = b * NNODE + chunk * 64 + wv * 16;
    const float* __restrict__ ar = atoms + (size_t)(grow0 + l16) * FDIM;

    bf16x8 A[2];
    #pragma unroll
    for (int ks = 0; ks < 2; ++ks) {
        const float4 p0 = *(const float4*)(ar + ks * 32 + qd * 8);
        const float4 p1 = *(const float4*)(ar + ks * 32 + qd * 8 + 4);
        A[ks][0] = f2bf(p0.x); A[ks][1] = f2bf(p0.y);
        A[ks][2] = f2bf(p0.z); A[ks][3] = f2bf(p0.w);
        A[ks][4] = f2bf(p1.x); A[ks][5] = f2bf(p1.y);
        A[ks][6] = f2bf(p1.z); A[ks][7] = f2bf(p1.w);
    }

    f32x4 C[4] = {{0,0,0,0},{0,0,0,0},{0,0,0,0},{0,0,0,0}};
    f32x4 Cs = {0,0,0,0};
    #pragma unroll
    for (int ks = 0; ks < 2; ++ks) {
        #pragma unroll
        for (int t = 0; t < 4; ++t)
            C[t] = __builtin_amdgcn_mfma_f32_16x16x32_bf16(A[ks], Bw[ks][t], C[t], 0, 0, 0);
        Cs = __builtin_amdgcn_mfma_f32_16x16x32_bf16(A[ks], Bs[ks], Cs, 0, 0, 0);
    }

    // C/D layout: col = l16, row = qd*4 + r
    #pragma unroll
    for (int t = 0; t < 4; ++t)
        #pragma unroll
        for (int r = 0; r < 4; ++r)
            hg[(size_t)(grow0 + qd * 4 + r) * FDIM + t * 16 + l16] =
                (unsigned short)f2bf(C[t][r]);

    if (l16 == 0) {
        #pragma unroll
        for (int r = 0; r < 4; ++r) s1[grow0 + qd * 4 + r] = Cs[r];
    } else if (l16 == 1) {
        #pragma unroll
        for (int r = 0; r < 4; ++r) s2[grow0 + qd * 4 + r] = Cs[r];
    }
}

// ---- k2: masked softmax over <=8 unique neighbors + bf16 gather ----------
// 256 threads, 64 rows/block, grid 1024; b = bid&63 -> gathers XCD-L2-hot.
__global__ __launch_bounds__(256) void gat_k2(
    const unsigned short* __restrict__ hg,  // (B*N, 64) bf16
    const float* __restrict__ s1g,          // (B*N)
    const float* __restrict__ s2g,          // (B*N)
    const int*   __restrict__ edges,        // (B*N, 8) int32
    float* __restrict__ out)                // (B*N, 64)
{
    __shared__ float s2l[NNODE];            // 4 KB
    __shared__ int   el[64 * DEG];          // 2 KB
    __shared__ float s1l[64];

    const int tid = threadIdx.x;
    const int bid = blockIdx.x;
    const int b     = bid & 63;
    const int chunk = bid >> 6;
    const int rowbase = b * NNODE + chunk * 64;

    ((float4*)s2l)[tid] = ((const float4*)(s2g + b * NNODE))[tid];
    ((int2*)el)[tid]    = ((const int2*)(edges + (size_t)rowbase * DEG))[tid];
    if (tid < 64) s1l[tid] = s1g[rowbase + tid];
    __syncthreads();

    const int lane = tid & 63;
    const int wv   = tid >> 6;
    const unsigned short* __restrict__ hb = hg + (size_t)b * NNODE * FDIM;

    #pragma unroll 2
    for (int i = 0; i < 16; ++i) {
        const int rl = wv * 16 + i;
        int ej[DEG];
        #pragma unroll
        for (int k = 0; k < DEG; ++k) ej[k] = el[rl * DEG + k];

        const float si = s1l[rl];
        float e[DEG], mx = -INFINITY;
        #pragma unroll
        for (int k = 0; k < DEG; ++k) {
            float v = si + s2l[ej[k]];
            v = (v > 0.f) ? v : ALPHA * v;           // LeakyReLU
            e[k] = v; mx = fmaxf(mx, v);
        }
        float wgt[DEG], wsum = 0.f;
        #pragma unroll
        for (int k = 0; k < DEG; ++k) {
            bool kp = true;                           // dedupe: adj is boolean
            #pragma unroll
            for (int m = 0; m < DEG; ++m)
                if (m < k && ej[m] == ej[k]) kp = false;
            const float w = kp ? __expf(e[k] - mx) : 0.f;
            wgt[k] = w; wsum += w;
        }
        const float inv = 1.f / wsum;

        float acc = 0.f;
        #pragma unroll
        for (int k = 0; k < DEG; ++k)
            acc = fmaf(wgt[k] * inv, bf2f(hb[(size_t)ej[k] * FDIM + lane]), acc);

        out[(size_t)(rowbase + rl) * FDIM + lane] = (acc > 0.f) ? acc : (__expf(acc) - 1.f);
    }
}

extern "C" void kernel_launch(void* const* d_in, const int* in_sizes, int n_in,
                              void* d_out, int out_size, void* d_ws, size_t ws_size,
                              hipStream_t stream) {
    const float* atoms = (const float*)d_in[0];   // (64,1024,64) f32
    const int*   edges = (const int*)d_in[1];     // (64,1024,8) int32
    const float* W     = (const float*)d_in[2];   // (64,64) f32
    const float* a     = (const float*)d_in[3];   // (128,1) f32
    float* out = (float*)d_out;                   // (64,1024,64) f32

    const int rows = BATCH * NNODE;               // 65536

    unsigned short* hg = (unsigned short*)d_ws;   // rows*64 bf16 = 8.4 MB
    float* s1 = (float*)(hg + (size_t)rows * FDIM);
    float* s2 = s1 + rows;

    gat_k1<<<1024, 256, 0, stream>>>(atoms, W, a, hg, s1, s2);
    gat_k2<<<1024, 256, 0, stream>>>(hg, s1, s2, edges, out);
}